// Round 1
// baseline (583.077 us; speedup 1.0000x reference)
//
#include <hip/hip_runtime.h>

#define NB 16
#define LT 4096
#define ND 512
#define MBINS 1024
#define LMBDA 0.1f

__device__ __forceinline__ float2 cmulf(float2 a, float2 b) {
    return make_float2(a.x * b.x - a.y * b.y, a.x * b.y + a.y * b.x);
}

// ws layout: float [4][NB][MBINS] : q=0 -> sum|Qa|^2, q=1 -> sum|Qb|^2, q=2 -> Re C, q=3 -> Im C
// where C = sum_d conj(Qa)*Qb.

// Forward: one block = (batch b, 16 consecutive d). Real-pack z = a + i*b.
// 4096-pt FFT first+fourth quarters via 4x 1024-pt batched FFTs + twiddle combine.
__global__ __launch_bounds__(1024)
void cte_fwd_kernel(const float* __restrict__ A, const float* __restrict__ Bp,
                    float* __restrict__ ws) {
    __shared__ float2 z[1024 * 16];   // [t1][dl], dl fast -> conflict-free batched FFT
    __shared__ float2 tw[512];        // tw[r] = exp(-2*pi*i*r/1024)

    const int tid   = threadIdx.x;
    const int bb    = blockIdx.x >> 5;        // 16 batches
    const int chunk = blockIdx.x & 31;        // 32 d-chunks of 16
    const int d0    = chunk * 16;

    if (tid < 512) {
        float ang = -6.283185307179586f * (float)tid * (1.0f / 1024.0f);
        float s, c;
        sincosf(ang, &s, &c);
        tw[tid] = make_float2(c, s);
    }

    float2 X1[16], Z4[16];            // X[k] and X[(4096-k)%4096] accumulators
#pragma unroll
    for (int j = 0; j < 16; ++j) {
        X1[j] = make_float2(0.f, 0.f);
        Z4[j] = make_float2(0.f, 0.f);
    }

    const int dl = tid & 15;          // d lane within chunk
    const int g  = tid >> 4;          // k-group 0..63

    for (int t2 = 0; t2 < 4; ++t2) {
        __syncthreads();  // previous round's combine reads of z must finish
        // ---- coalesced load of subsequence x[4*t1 + t2] for 16 d ----
        for (int r = 0; r < 16; ++r) {
            int item = r * 1024 + tid;
            int dli  = item & 15;
            int t1   = item >> 4;
            size_t base = ((size_t)(bb * LT + 4 * t1 + t2)) * ND + d0 + dli;
            z[t1 * 16 + dli] = make_float2(A[base], Bp[base]);
        }
        __syncthreads();

        // ---- batched in-place DIF 1024-pt FFT over t1 (output bit-reversed) ----
        int m = 512, lm = 9;
        for (int st = 0; st < 10; ++st) {
            for (int r = 0; r < 8; ++r) {
                int item = r * 1024 + tid;
                int dli  = item & 15;
                int u    = item >> 4;                    // butterfly id [0,512)
                int j    = u & (m - 1);
                int i0   = ((u >> lm) << (lm + 1)) + j;
                int i1   = i0 + m;
                float2 w = tw[j << (9 - lm)];
                float2 a = z[i0 * 16 + dli];
                float2 c = z[i1 * 16 + dli];
                z[i0 * 16 + dli] = make_float2(a.x + c.x, a.y + c.y);
                float2 d = make_float2(a.x - c.x, a.y - c.y);
                z[i1 * 16 + dli] = cmulf(d, w);
            }
            m >>= 1; lm--;
            __syncthreads();
        }

        // ---- combine: X[k] += W4096^(t2*k) * Y[k]; X[4096-k] += conj(W) * Y[1024-k] ----
#pragma unroll
        for (int j = 0; j < 16; ++j) {
            int k   = g + 64 * j;
            int rk  = __brev((unsigned)k) >> 22;
            int k2  = (1024 - k) & 1023;
            int rk2 = __brev((unsigned)k2) >> 22;
            float2 Ya = z[rk * 16 + dl];
            float2 Yb = z[rk2 * 16 + dl];
            float ang = -1.5339807878856412e-03f * (float)(t2 * k);  // -2pi/4096 * t2*k
            float s, c;
            sincosf(ang, &s, &c);
            X1[j].x += c * Ya.x - s * Ya.y;
            X1[j].y += c * Ya.y + s * Ya.x;
            Z4[j].x += c * Yb.x + s * Yb.y;   // conj(w) * Yb
            Z4[j].y += c * Yb.y - s * Yb.x;
        }
    }

    // ---- unpack Qa/Qb, products, reduce over 16 d-lanes, atomic flush ----
#pragma unroll
    for (int j = 0; j < 16; ++j) {
        int k = g + 64 * j;
        float Ar = 0.5f * (X1[j].x + Z4[j].x);
        float Ai = 0.5f * (X1[j].y - Z4[j].y);
        float Br = 0.5f * (X1[j].y + Z4[j].y);
        float Bi = 0.5f * (Z4[j].x - X1[j].x);
        float da = Ar * Ar + Ai * Ai;
        float db = Br * Br + Bi * Bi;
        float cr = Ar * Br + Ai * Bi;
        float ci = Ar * Bi - Ai * Br;
        for (int msk = 1; msk < 16; msk <<= 1) {
            da += __shfl_xor(da, msk);
            db += __shfl_xor(db, msk);
            cr += __shfl_xor(cr, msk);
            ci += __shfl_xor(ci, msk);
        }
        if (dl == 0) {
            atomicAdd(&ws[0 * NB * MBINS + bb * MBINS + k], da);
            atomicAdd(&ws[1 * NB * MBINS + bb * MBINS + k], db);
            atomicAdd(&ws[2 * NB * MBINS + bb * MBINS + k], cr);
            atomicAdd(&ws[3 * NB * MBINS + bb * MBINS + k], ci);
        }
    }
}

// Inverse: block = (b, dir). S = C/den (dir 0) or conj(C)/den (dir 1), padded to 4096,
// complex IFFT (in-place DIF, conj twiddles, bit-reversed output indexing), real part.
__global__ __launch_bounds__(256)
void cte_inv_kernel(const float* __restrict__ ws, float* __restrict__ out) {
    __shared__ float2 zz[4096];
    __shared__ float2 tw[2048];       // tw[r] = exp(+2*pi*i*r/4096)
    const int tid = threadIdx.x;
    const int bb  = blockIdx.x >> 1;
    const int dir = blockIdx.x & 1;

    for (int i = tid; i < 2048; i += 256) {
        float ang = 6.283185307179586f * (float)i * (1.0f / 4096.0f);
        float s, c;
        sincosf(ang, &s, &c);
        tw[i] = make_float2(c, s);
    }
    for (int i = tid; i < 4096; i += 256) {
        float2 v = make_float2(0.f, 0.f);
        if (i < MBINS) {
            float den = ws[(dir ? 1 : 0) * NB * MBINS + bb * MBINS + i] + LMBDA;
            float cr  = ws[2 * NB * MBINS + bb * MBINS + i];
            float ci  = ws[3 * NB * MBINS + bb * MBINS + i];
            if (dir) ci = -ci;
            v = make_float2(cr / den, ci / den);
        }
        zz[i] = v;
    }
    __syncthreads();

    int m = 2048, lm = 11;
    for (int st = 0; st < 12; ++st) {
        for (int r = 0; r < 8; ++r) {
            int u  = r * 256 + tid;               // 2048 butterflies
            int j  = u & (m - 1);
            int i0 = ((u >> lm) << (lm + 1)) + j;
            int i1 = i0 + m;
            float2 w = tw[j << (11 - lm)];
            float2 a = zz[i0];
            float2 c = zz[i1];
            zz[i0] = make_float2(a.x + c.x, a.y + c.y);
            float2 d = make_float2(a.x - c.x, a.y - c.y);
            zz[i1] = cmulf(d, w);
        }
        m >>= 1; lm--;
        __syncthreads();
    }

    const float scale = 1.0f / 4096.0f;
    for (int t = tid; t < 4096; t += 256) {
        int rt = __brev((unsigned)t) >> 20;       // R[t] sits at bit-reversed slot
        float val = zz[rt].x * scale;
        int col = (dir == 0) ? (4095 - t) : (4096 + t);
        out[bb * 8192 + col] = val;
    }
}

extern "C" void kernel_launch(void* const* d_in, const int* in_sizes, int n_in,
                              void* d_out, int out_size, void* d_ws, size_t ws_size,
                              hipStream_t stream) {
    const float* a = (const float*)d_in[0];
    const float* b = (const float*)d_in[1];
    // d_in[2] (offsets) only determines shapes; numerically unused.
    float* out = (float*)d_out;
    float* ws  = (float*)d_ws;

    hipMemsetAsync(d_ws, 0, 4 * NB * MBINS * sizeof(float), stream);
    cte_fwd_kernel<<<dim3(NB * 32), dim3(1024), 0, stream>>>(a, b, ws);
    cte_inv_kernel<<<dim3(NB * 2), dim3(256), 0, stream>>>(ws, out);
}

// Round 2
// 299.997 us; speedup vs baseline: 1.9436x; 1.9436x over previous
//
#include <hip/hip_runtime.h>

#define NB 16
#define LT 4096
#define ND 512
#define MBINS 1024
#define LMBDA 0.1f

__device__ __forceinline__ float2 cmulf(float2 a, float2 b) {
    return make_float2(a.x * b.x - a.y * b.y, a.x * b.y + a.y * b.x);
}

// ws layout: float [4][NB][MBINS] : q=0 -> sum|Qa|^2, q=1 -> sum|Qb|^2, q=2 -> Re C, q=3 -> Im C
// where C = sum_d conj(Qa)*Qb.

// Forward: one block = (batch b, 16 consecutive d). Real-pack z = a + i*b.
// 4096-pt FFT first+fourth quarters via 4x 1024-pt batched FFTs + twiddle combine.
// __launch_bounds__(1024, 4): LDS (132 KB) limits us to 1 block/CU = 4 waves/SIMD
// anyway, so allow the full 128-VGPR budget -> 64-float accumulators stay in regs.
__global__ __launch_bounds__(1024, 4)
void cte_fwd_kernel(const float* __restrict__ A, const float* __restrict__ Bp,
                    float* __restrict__ ws) {
    __shared__ float2 z[1024 * 16];   // [t1][dl], dl fast -> conflict-free batched FFT
    __shared__ float2 tw[512];        // tw[r] = exp(-2*pi*i*r/1024)

    const int tid   = threadIdx.x;
    const int bb    = blockIdx.x >> 5;        // 16 batches
    const int chunk = blockIdx.x & 31;        // 32 d-chunks of 16
    const int d0    = chunk * 16;

    if (tid < 512) {
        float ang = -6.283185307179586f * (float)tid * (1.0f / 1024.0f);
        float s, c;
        sincosf(ang, &s, &c);
        tw[tid] = make_float2(c, s);
    }

    float2 X1[16], Z4[16];            // X[k] and X[(4096-k)%4096] accumulators
#pragma unroll
    for (int j = 0; j < 16; ++j) {
        X1[j] = make_float2(0.f, 0.f);
        Z4[j] = make_float2(0.f, 0.f);
    }

    const int dl = tid & 15;          // d lane within chunk
    const int g  = tid >> 4;          // k-group 0..63

    for (int t2 = 0; t2 < 4; ++t2) {
        __syncthreads();  // previous round's combine reads of z must finish
        // ---- coalesced load of subsequence x[4*t1 + t2] for 16 d ----
        for (int r = 0; r < 16; ++r) {
            int item = r * 1024 + tid;
            int dli  = item & 15;
            int t1   = item >> 4;
            size_t base = ((size_t)(bb * LT + 4 * t1 + t2)) * ND + d0 + dli;
            z[t1 * 16 + dli] = make_float2(A[base], Bp[base]);
        }
        __syncthreads();

        // ---- batched in-place DIF 1024-pt FFT over t1 (output bit-reversed) ----
        int m = 512, lm = 9;
        for (int st = 0; st < 10; ++st) {
            for (int r = 0; r < 8; ++r) {
                int item = r * 1024 + tid;
                int dli  = item & 15;
                int u    = item >> 4;                    // butterfly id [0,512)
                int j    = u & (m - 1);
                int i0   = ((u >> lm) << (lm + 1)) + j;
                int i1   = i0 + m;
                float2 w = tw[j << (9 - lm)];
                float2 a = z[i0 * 16 + dli];
                float2 c = z[i1 * 16 + dli];
                z[i0 * 16 + dli] = make_float2(a.x + c.x, a.y + c.y);
                float2 d = make_float2(a.x - c.x, a.y - c.y);
                z[i1 * 16 + dli] = cmulf(d, w);
            }
            m >>= 1; lm--;
            __syncthreads();
        }

        // ---- combine: X[k] += W4096^(t2*k) * Y[k]; X[4096-k] += conj(W) * Y[1024-k] ----
        // Incremental twiddle: w(k=g+64j) = w0 * wstep^j  (1 sincosf instead of 16)
        float2 w, wstep;
        {
            float s, c;
            float ang0 = -1.5339807878856412e-03f * (float)(t2 * g);   // -2pi/4096 * t2*g
            sincosf(ang0, &s, &c);
            w = make_float2(c, s);
            float angs = -9.8174770424681035e-02f * (float)t2;          // -2pi/4096 * 64*t2
            sincosf(angs, &s, &c);
            wstep = make_float2(c, s);
        }
#pragma unroll
        for (int j = 0; j < 16; ++j) {
            int k   = g + 64 * j;
            int rk  = __brev((unsigned)k) >> 22;
            int k2  = (1024 - k) & 1023;
            int rk2 = __brev((unsigned)k2) >> 22;
            float2 Ya = z[rk * 16 + dl];
            float2 Yb = z[rk2 * 16 + dl];
            X1[j].x += w.x * Ya.x - w.y * Ya.y;
            X1[j].y += w.x * Ya.y + w.y * Ya.x;
            Z4[j].x += w.x * Yb.x + w.y * Yb.y;   // conj(w) * Yb
            Z4[j].y += w.x * Yb.y - w.y * Yb.x;
            w = cmulf(w, wstep);
        }
    }

    // ---- unpack Qa/Qb, products, reduce over 16 d-lanes, atomic flush ----
#pragma unroll
    for (int j = 0; j < 16; ++j) {
        int k = g + 64 * j;
        float Ar = 0.5f * (X1[j].x + Z4[j].x);
        float Ai = 0.5f * (X1[j].y - Z4[j].y);
        float Br = 0.5f * (X1[j].y + Z4[j].y);
        float Bi = 0.5f * (Z4[j].x - X1[j].x);
        float da = Ar * Ar + Ai * Ai;
        float db = Br * Br + Bi * Bi;
        float cr = Ar * Br + Ai * Bi;
        float ci = Ar * Bi - Ai * Br;
        for (int msk = 1; msk < 16; msk <<= 1) {
            da += __shfl_xor(da, msk);
            db += __shfl_xor(db, msk);
            cr += __shfl_xor(cr, msk);
            ci += __shfl_xor(ci, msk);
        }
        if (dl == 0) {
            atomicAdd(&ws[0 * NB * MBINS + bb * MBINS + k], da);
            atomicAdd(&ws[1 * NB * MBINS + bb * MBINS + k], db);
            atomicAdd(&ws[2 * NB * MBINS + bb * MBINS + k], cr);
            atomicAdd(&ws[3 * NB * MBINS + bb * MBINS + k], ci);
        }
    }
}

// Inverse: block = (b, dir). S = C/den (dir 0) or conj(C)/den (dir 1), padded to 4096,
// complex IFFT (in-place DIF, conj twiddles, bit-reversed output indexing), real part.
__global__ __launch_bounds__(256)
void cte_inv_kernel(const float* __restrict__ ws, float* __restrict__ out) {
    __shared__ float2 zz[4096];
    __shared__ float2 tw[2048];       // tw[r] = exp(+2*pi*i*r/4096)
    const int tid = threadIdx.x;
    const int bb  = blockIdx.x >> 1;
    const int dir = blockIdx.x & 1;

    for (int i = tid; i < 2048; i += 256) {
        float ang = 6.283185307179586f * (float)i * (1.0f / 4096.0f);
        float s, c;
        sincosf(ang, &s, &c);
        tw[i] = make_float2(c, s);
    }
    for (int i = tid; i < 4096; i += 256) {
        float2 v = make_float2(0.f, 0.f);
        if (i < MBINS) {
            float den = ws[(dir ? 1 : 0) * NB * MBINS + bb * MBINS + i] + LMBDA;
            float cr  = ws[2 * NB * MBINS + bb * MBINS + i];
            float ci  = ws[3 * NB * MBINS + bb * MBINS + i];
            if (dir) ci = -ci;
            v = make_float2(cr / den, ci / den);
        }
        zz[i] = v;
    }
    __syncthreads();

    int m = 2048, lm = 11;
    for (int st = 0; st < 12; ++st) {
        for (int r = 0; r < 8; ++r) {
            int u  = r * 256 + tid;               // 2048 butterflies
            int j  = u & (m - 1);
            int i0 = ((u >> lm) << (lm + 1)) + j;
            int i1 = i0 + m;
            float2 w = tw[j << (11 - lm)];
            float2 a = zz[i0];
            float2 c = zz[i1];
            zz[i0] = make_float2(a.x + c.x, a.y + c.y);
            float2 d = make_float2(a.x - c.x, a.y - c.y);
            zz[i1] = cmulf(d, w);
        }
        m >>= 1; lm--;
        __syncthreads();
    }

    const float scale = 1.0f / 4096.0f;
    for (int t = tid; t < 4096; t += 256) {
        int rt = __brev((unsigned)t) >> 20;       // R[t] sits at bit-reversed slot
        float val = zz[rt].x * scale;
        int col = (dir == 0) ? (4095 - t) : (4096 + t);
        out[bb * 8192 + col] = val;
    }
}

extern "C" void kernel_launch(void* const* d_in, const int* in_sizes, int n_in,
                              void* d_out, int out_size, void* d_ws, size_t ws_size,
                              hipStream_t stream) {
    const float* a = (const float*)d_in[0];
    const float* b = (const float*)d_in[1];
    // d_in[2] (offsets) only determines shapes; numerically unused.
    float* out = (float*)d_out;
    float* ws  = (float*)d_ws;

    hipMemsetAsync(d_ws, 0, 4 * NB * MBINS * sizeof(float), stream);
    cte_fwd_kernel<<<dim3(NB * 32), dim3(1024), 0, stream>>>(a, b, ws);
    cte_inv_kernel<<<dim3(NB * 2), dim3(256), 0, stream>>>(ws, out);
}